// Round 8
// baseline (2570.876 us; speedup 1.0000x reference)
//
#include <hip/hip_runtime.h>
#include <math.h>

#define B_ 8192
#define H_ 1024
#define LDP0 136
#define LDTD 100   // Td column stride (floats): 100%32=4, 16B-aligned

typedef short bfrag __attribute__((ext_vector_type(8)));
typedef float f4v  __attribute__((ext_vector_type(4)));

union U8 { unsigned short u[8]; uint4 v; };

__device__ __forceinline__ float sigf(float x){ return 1.0f/(1.0f+__expf(-x)); }

// pack high halves of two fp32 (bf16-valued) into one u32
__device__ __forceinline__ unsigned int pkhi(unsigned int u1, unsigned int u0){
  return __builtin_amdgcn_perm(u1, u0, 0x07060302u);
}

// exact 3-way truncation split of 8 fp32 -> 3 packed uint4 (bf16x8 planes)
__device__ __forceinline__ void split3(const float* av, uint4& vh, uint4& vm, uint4& vl){
  unsigned int uh[8], um[8], ul[8];
  #pragma unroll
  for(int e=0;e<8;e++){
    unsigned int ua = __float_as_uint(av[e]);
    unsigned int h = ua & 0xFFFF0000u;
    float r1 = av[e] - __uint_as_float(h);
    unsigned int mm = __float_as_uint(r1) & 0xFFFF0000u;
    float l = r1 - __uint_as_float(mm);   // exact
    uh[e]=h; um[e]=mm; ul[e]=__float_as_uint(l);
  }
  vh = make_uint4(pkhi(uh[1],uh[0]), pkhi(uh[3],uh[2]), pkhi(uh[5],uh[4]), pkhi(uh[7],uh[6]));
  vm = make_uint4(pkhi(um[1],um[0]), pkhi(um[3],um[2]), pkhi(um[5],um[4]), pkhi(um[7],um[6]));
  vl = make_uint4(pkhi(ul[1],ul[0]), pkhi(ul[3],ul[2]), pkhi(ul[5],ul[4]), pkhi(ul[7],ul[6]));
}

// ---------------- K1: s1 = sigmoid(x @ W1 + b1) ----------------
__global__ void k1_s1(const float* __restrict__ x, const float* __restrict__ W1,
                      const float* __restrict__ b1, float* __restrict__ s1o){
  __shared__ float xs[16];
  int b = blockIdx.x, t = threadIdx.x;
  if(t < 16) xs[t] = x[b*16 + t];
  __syncthreads();
  for(int h = t; h < H_; h += 256){
    float acc = b1[h];
    #pragma unroll
    for(int j=0;j<16;j++) acc += xs[j]*W1[j*H_ + h];
    s1o[(size_t)b*H_ + h] = sigf(acc);
  }
}

// ---------------- K2: s2 = sigmoid(softplus @ W2 + b2), softplus = -log(1-s1) ----
__global__ __launch_bounds__(256,3) void k2_s2(const float* __restrict__ s1,
                      const float* __restrict__ W2, const float* __restrict__ b2,
                      float* __restrict__ s2o){
  __shared__ __align__(16) float As[32*LDP0];
  __shared__ __align__(16) float Bs[32*LDP0];
  int t = threadIdx.x, tx = t & 15, ty = t >> 4;
  int m0 = blockIdx.x * 128, n0 = blockIdx.y * 128;
  int jj = t & 31, rb4 = (t >> 5) * 4;
  float acc[8][8];
  #pragma unroll
  for(int i=0;i<8;i++){
    #pragma unroll
    for(int k=0;k<8;k++) acc[i][k]=0.f; }

  for(int jt=0; jt<32; jt++){
    int j0 = jt*32;
    __syncthreads();
    #pragma unroll
    for(int g=0; g<4; g++){
      #pragma unroll
      for(int i=0;i<4;i++){
        int r = rb4 + i + 32*g;
        As[jj*LDP0 + r] = -__logf(1.0f - s1[(size_t)(m0+r)*H_ + j0 + jj]);
      }
    }
    { int jB = t >> 3, kb = (t & 7) * 16;
      const float* src = &W2[(size_t)(j0 + jB)*H_ + n0 + kb];
      #pragma unroll
      for(int c=0;c<4;c++) *(float4*)&Bs[jB*LDP0 + kb + 4*c] = *(const float4*)(src + 4*c);
    }
    __syncthreads();
    #pragma unroll 8
    for(int j=0;j<32;j++){
      float4 a0 = *(const float4*)&As[j*LDP0 + 8*ty];
      float4 a1f= *(const float4*)&As[j*LDP0 + 8*ty+4];
      float4 b0 = *(const float4*)&Bs[j*LDP0 + 4*tx];
      float4 b1f= *(const float4*)&Bs[j*LDP0 + 64 + 4*tx];
      float aa[8] = {a0.x,a0.y,a0.z,a0.w,a1f.x,a1f.y,a1f.z,a1f.w};
      float bb[8] = {b0.x,b0.y,b0.z,b0.w,b1f.x,b1f.y,b1f.z,b1f.w};
      #pragma unroll
      for(int i=0;i<8;i++){
        #pragma unroll
        for(int k=0;k<8;k++) acc[i][k] += aa[i]*bb[k]; }
    }
  }
  float4 bb0 = *(const float4*)&b2[n0 + 4*tx];
  float4 bb1 = *(const float4*)&b2[n0 + 64 + 4*tx];
  #pragma unroll
  for(int i=0;i<8;i++){
    size_t r = (size_t)(m0 + 8*ty + i)*H_;
    float4 o0 = make_float4(sigf(acc[i][0]+bb0.x), sigf(acc[i][1]+bb0.y),
                            sigf(acc[i][2]+bb0.z), sigf(acc[i][3]+bb0.w));
    float4 o1 = make_float4(sigf(acc[i][4]+bb1.x), sigf(acc[i][5]+bb1.y),
                            sigf(acc[i][6]+bb1.z), sigf(acc[i][7]+bb1.w));
    *(float4*)&s2o[r + n0 + 4*tx] = o0;
    *(float4*)&s2o[r + n0 + 64 + 4*tx] = o1;
  }
}

// ---------------- K3: u = (w3*s2) @ W2^T ----------------
__global__ __launch_bounds__(256,3) void k3_u(const float* __restrict__ s2,
                      const float* __restrict__ W2, const float* __restrict__ W3,
                      float* __restrict__ u){
  __shared__ __align__(16) float As[32*LDP0];
  __shared__ __align__(16) float Bs[32*LDP0];
  int t = threadIdx.x, tx = t & 15, ty = t >> 4;
  int m0 = blockIdx.x * 128, n0 = blockIdx.y * 128;
  int jj = t & 31, rb4 = (t >> 5) * 4;
  float acc[8][8];
  #pragma unroll
  for(int i=0;i<8;i++){
    #pragma unroll
    for(int k=0;k<8;k++) acc[i][k]=0.f; }

  for(int kt=0; kt<32; kt++){
    int k0 = kt*32;
    __syncthreads();
    float w3v = W3[k0 + jj];
    #pragma unroll
    for(int g=0; g<4; g++){
      #pragma unroll
      for(int i=0;i<4;i++){
        int r = rb4 + i + 32*g;
        As[jj*LDP0 + r] = w3v * s2[(size_t)(m0+r)*H_ + k0 + jj];
      }
    }
    { int jcol = t >> 1, kb = (t & 1) * 16;
      const float* src = &W2[(size_t)(n0 + jcol)*H_ + k0 + kb];
      #pragma unroll
      for(int c=0;c<16;c++) Bs[(kb+c)*LDP0 + jcol] = src[c];
    }
    __syncthreads();
    #pragma unroll 8
    for(int j=0;j<32;j++){
      float4 a0 = *(const float4*)&As[j*LDP0 + 8*ty];
      float4 a1f= *(const float4*)&As[j*LDP0 + 8*ty+4];
      float4 b0 = *(const float4*)&Bs[j*LDP0 + 4*tx];
      float4 b1f= *(const float4*)&Bs[j*LDP0 + 64 + 4*tx];
      float aa[8] = {a0.x,a0.y,a0.z,a0.w,a1f.x,a1f.y,a1f.z,a1f.w};
      float bb[8] = {b0.x,b0.y,b0.z,b0.w,b1f.x,b1f.y,b1f.z,b1f.w};
      #pragma unroll
      for(int i=0;i<8;i++){
        #pragma unroll
        for(int k=0;k<8;k++) acc[i][k] += aa[i]*bb[k]; }
    }
  }
  #pragma unroll
  for(int i=0;i<8;i++){
    size_t r = (size_t)(m0 + 8*ty + i)*H_;
    *(float4*)&u[r + n0 + 4*tx]      = make_float4(acc[i][0],acc[i][1],acc[i][2],acc[i][3]);
    *(float4*)&u[r + n0 + 64 + 4*tx] = make_float4(acc[i][4],acc[i][5],acc[i][6],acc[i][7]);
  }
}

// ---------------- KF: F64[j][p] = W1[8+(p>>3)][j]*W1[8+(p&7)][j] ----------------
__global__ void kF(const float* __restrict__ W1, float* __restrict__ F64){
  int e = blockIdx.x*256 + threadIdx.x;
  int j = e >> 6, p = e & 63;
  F64[e] = W1[(8+(p>>3))*H_ + j] * W1[(8+(p&7))*H_ + j];
}

// ---------------- K5a: Hz1M = D1 @ F64 ----------------
__global__ __launch_bounds__(256) void k5a(const float* __restrict__ s1,
                      const float* __restrict__ u, const float* __restrict__ F64,
                      float* __restrict__ Hz1M){
  __shared__ __align__(16) float As[32*72];
  __shared__ __align__(16) float Bs[32*72];
  int t = threadIdx.x, tx = t & 15, ty = t >> 4;
  int m0 = blockIdx.x * 64;
  int jj = t & 31, rb8 = (t >> 5) * 8;
  float acc[4][4];
  #pragma unroll
  for(int i=0;i<4;i++){
    #pragma unroll
    for(int k=0;k<4;k++) acc[i][k]=0.f; }

  for(int jt=0; jt<32; jt++){
    int j0 = jt*32;
    __syncthreads();
    #pragma unroll
    for(int g=0; g<8; g++){
      int r = rb8 + g;
      float s = s1[(size_t)(m0+r)*H_ + j0 + jj];
      As[jj*72 + r] = s*(1.0f-s)*u[(size_t)(m0+r)*H_ + j0 + jj];
    }
    { int jB = t >> 3, cb = (t & 7) * 8;
      const float* src = &F64[(j0 + jB)*64 + cb];
      *(float4*)&Bs[jB*72 + cb]   = *(const float4*)(src);
      *(float4*)&Bs[jB*72 + cb+4] = *(const float4*)(src+4);
    }
    __syncthreads();
    #pragma unroll 8
    for(int j=0;j<32;j++){
      float4 a4 = *(const float4*)&As[j*72 + 4*ty];
      float4 b4 = *(const float4*)&Bs[j*72 + 4*tx];
      float aa[4] = {a4.x,a4.y,a4.z,a4.w};
      float bb[4] = {b4.x,b4.y,b4.z,b4.w};
      #pragma unroll
      for(int i=0;i<4;i++){
        #pragma unroll
        for(int k=0;k<4;k++) acc[i][k] += aa[i]*bb[k]; }
    }
  }
  #pragma unroll
  for(int i=0;i<4;i++)
    *(float4*)&Hz1M[(size_t)(m0+4*ty+i)*64 + 4*tx] =
      make_float4(acc[i][0],acc[i][1],acc[i][2],acc[i][3]);
}

// ---------------- K5b: dq16[b][0:8]=dLdq, [8:16]=c1 ----------------
__global__ void k5b(const float* __restrict__ s1, const float* __restrict__ u,
                    const float* __restrict__ W1, const float* __restrict__ x,
                    float* __restrict__ dq16){
  int wid = threadIdx.x >> 6, lane = threadIdx.x & 63;
  int b = blockIdx.x*4 + wid;
  float qd[8];
  #pragma unroll
  for(int i=0;i<8;i++) qd[i] = x[b*16 + 8 + i];
  float accd[8] = {0,0,0,0,0,0,0,0};
  float accc[8] = {0,0,0,0,0,0,0,0};
  for(int jb=0;jb<16;jb++){
    int j = jb*64 + lane;
    float s1v = s1[(size_t)b*H_+j], uv = u[(size_t)b*H_+j];
    float g1 = s1v*uv;
    float d1 = (1.0f - s1v)*g1;
    float w1q = 0.f;
    #pragma unroll
    for(int i=0;i<8;i++){ float w = W1[i*H_+j]; accd[i] += g1*w; w1q += qd[i]*w; }
    float dw = d1*w1q;
    #pragma unroll
    for(int m=0;m<8;m++) accc[m] += dw * W1[(8+m)*H_+j];
  }
  #pragma unroll
  for(int i=0;i<8;i++){
    #pragma unroll
    for(int off=1; off<64; off<<=1){
      accd[i] += __shfl_xor(accd[i], off, 64);
      accc[i] += __shfl_xor(accc[i], off, 64);
    }
  }
  if(lane==0){
    #pragma unroll
    for(int i=0;i<8;i++){ dq16[b*16+i] = accd[i]; dq16[b*16+8+i] = accc[i]; }
  }
}

// ---------------- KW2T: W2 -> 3 transposed bf16 EXACT-truncation planes [k][j] ----
__global__ void kW2T(const float* __restrict__ W2, unsigned short* __restrict__ Wh,
                     unsigned short* __restrict__ Wm, unsigned short* __restrict__ Wl){
  __shared__ float tile[32][132];
  int j0 = blockIdx.x * 32, k0 = blockIdx.y * 128;
  int t = threadIdx.x;
  int lr = t >> 3, lc0 = (t & 7) * 16;
  const float* src = &W2[(size_t)(j0+lr)*H_ + k0 + lc0];
  #pragma unroll
  for(int c=0;c<16;c+=4) *(float4*)&tile[lr][lc0+c] = *(const float4*)(src + c);
  __syncthreads();
  int k = t >> 1;
  #pragma unroll
  for(int o2=0;o2<2;o2++){
    int oc = (t&1)*2 + o2;
    float av[8];
    #pragma unroll
    for(int e=0;e<8;e++) av[e] = tile[oc*8+e][k];
    uint4 vh, vm, vl;
    split3(av, vh, vm, vl);
    size_t o = (size_t)(k0+k)*H_ + j0 + oc*8;
    *(uint4*)&Wh[o] = vh; *(uint4*)&Wm[o] = vm; *(uint4*)&Wl[o] = vl;
  }
}

// ---------------- K4: bf16x8 exact-split MFMA T-GEMM + d2 contraction ----------------
// Block: 8 samples x 128 k-cols, BK=32 (rows = 32 shorts = 4 chunks of 16B).
// XOR swizzle: chunk c of row r at slot (c ^ ((r>>1)&3)) -> every 8-lane group of
// every b128 read/write covers 8 distinct bank-quads (verified per pattern).
// LDS 40KB -> 4 blocks/CU (16 waves/CU) to overlap barrier stalls across blocks.
// A rows: r<64: T[s=r>>3][m=r&7]; [64,72): G[s]; [72,80): pad (zeroed once).
// B tiles prefetched into registers during previous MFMA phase.
__global__ __launch_bounds__(256,4) void k4_mfma(
    const float* __restrict__ s1, const float* __restrict__ s2,
    const float* __restrict__ x,  const float* __restrict__ W1,
    const unsigned short* __restrict__ W2Th, const unsigned short* __restrict__ W2Tm,
    const unsigned short* __restrict__ W2Tl,
    const float* __restrict__ W3, float* __restrict__ Mpart){
  __shared__ union {
    struct { unsigned short A[3][80*32]; unsigned short Bt[3][128*32]; } st; // 39936B
    float Td[64*LDTD];                                                      // 25600B
  } sm;
  __shared__ float qds[8][8];

  int t = threadIdx.x;
  int wv = t >> 6, lane = t & 63;
  int kb = blockIdx.x >> 10, sgp = blockIdx.x & 1023;
  int b0 = sgp*8, k0 = kb*128;

  if(t < 64){ qds[t>>3][t&7] = x[(b0+(t>>3))*16 + 8 + (t&7)]; }
  // zero pad rows [72,80): 3 planes x 8 rows x 32 shorts
  if(t < 96){
    int p = t >> 5, q = t & 31;
    *(uint4*)&sm.st.A[p][72*32 + q*8] = make_uint4(0,0,0,0);
  }

  f4v acc[5][2];
  #pragma unroll
  for(int mt=0;mt<5;mt++){
    #pragma unroll
    for(int n2=0;n2<2;n2++){ acc[mt][n2][0]=0.f; acc[mt][n2][1]=0.f; acc[mt][n2][2]=0.f; acc[mt][n2][3]=0.f; }
  }

  int fr_m = lane & 15, fr_q = lane >> 4;
  int fro = ((fr_q ^ ((fr_m >> 1) & 3)) * 8);   // fragment chunk offset (shorts)
  // A staging: one T-row chunk per thread
  int ar = t >> 2, ac = t & 3;
  int as_ = ar >> 3, am = ar & 7;
  int ao_ = ar*32 + ((ac ^ ((ar >> 1) & 3)) * 8);
  // B staging: row bn, 2 chunks
  int bn = t >> 1, bh2 = t & 1;
  int bsw = (bn >> 1) & 3;
  int bo0 = bn*32 + (((bh2*2+0) ^ bsw) * 8);
  int bo1 = bn*32 + (((bh2*2+1) ^ bsw) * 8);
  // G staging (t<32): one G-row chunk
  int gs = t >> 2, gc = t & 3;
  int go = (64+gs)*32 + ((gc ^ ((gs >> 1) & 3)) * 8);

  // prefetch B for jt=0
  uint4 pfb0, pfb1, pfb2, pfb3, pfb4, pfb5;
  {
    size_t g0 = (size_t)(k0+bn)*H_ + bh2*16;
    pfb0 = *(const uint4*)&W2Th[g0]; pfb1 = *(const uint4*)&W2Th[g0+8];
    pfb2 = *(const uint4*)&W2Tm[g0]; pfb3 = *(const uint4*)&W2Tm[g0+8];
    pfb4 = *(const uint4*)&W2Tl[g0]; pfb5 = *(const uint4*)&W2Tl[g0+8];
  }

  for(int jt=0; jt<32; jt++){
    int j0 = jt*32;
    __syncthreads();
    // ---- A stage: T-row chunk (load, multiply, split, write) ----
    {
      const float* wp = &W1[(size_t)(8+am)*H_ + j0 + ac*8];
      const float* sp = &s1[(size_t)(b0+as_)*H_ + j0 + ac*8];
      float4 w0 = *(const float4*)wp, w1v = *(const float4*)(wp+4);
      float4 sa = *(const float4*)sp, sb = *(const float4*)(sp+4);
      float av[8];
      av[0]=w0.x*sa.x; av[1]=w0.y*sa.y; av[2]=w0.z*sa.z; av[3]=w0.w*sa.w;
      av[4]=w1v.x*sb.x; av[5]=w1v.y*sb.y; av[6]=w1v.z*sb.z; av[7]=w1v.w*sb.w;
      uint4 vh, vm, vl;
      split3(av, vh, vm, vl);
      *(uint4*)&sm.st.A[0][ao_] = vh;
      *(uint4*)&sm.st.A[1][ao_] = vm;
      *(uint4*)&sm.st.A[2][ao_] = vl;
    }
    // ---- B stage: write prefetched registers ----
    *(uint4*)&sm.st.Bt[0][bo0] = pfb0;  *(uint4*)&sm.st.Bt[0][bo1] = pfb1;
    *(uint4*)&sm.st.Bt[1][bo0] = pfb2;  *(uint4*)&sm.st.Bt[1][bo1] = pfb3;
    *(uint4*)&sm.st.Bt[2][bo0] = pfb4;  *(uint4*)&sm.st.Bt[2][bo1] = pfb5;
    // ---- G stage (threads 0..31) ----
    if(t < 32){
      const float* sp = &s1[(size_t)(b0+gs)*H_ + j0 + gc*8];
      float4 sa = *(const float4*)sp, sb = *(const float4*)(sp+4);
      float g8[8] = {0,0,0,0,0,0,0,0};
      #pragma unroll
      for(int i=0;i<8;i++){
        float q = qds[gs][i];
        const float* wp = &W1[(size_t)i*H_ + j0 + gc*8];
        float4 a0 = *(const float4*)wp, a1 = *(const float4*)(wp+4);
        g8[0] += q*a0.x; g8[1] += q*a0.y; g8[2] += q*a0.z; g8[3] += q*a0.w;
        g8[4] += q*a1.x; g8[5] += q*a1.y; g8[6] += q*a1.z; g8[7] += q*a1.w;
      }
      float av[8];
      av[0]=g8[0]*sa.x; av[1]=g8[1]*sa.y; av[2]=g8[2]*sa.z; av[3]=g8[3]*sa.w;
      av[4]=g8[4]*sb.x; av[5]=g8[5]*sb.y; av[6]=g8[6]*sb.z; av[7]=g8[7]*sb.w;
      uint4 vh, vm, vl;
      split3(av, vh, vm, vl);
      *(uint4*)&sm.st.A[0][go] = vh;
      *(uint4*)&sm.st.A[1][go] = vm;
      *(uint4*)&sm.st.A[2][go] = vl;
    }
    __syncthreads();
    // ---- prefetch B for jt+1 (completes during MFMA phase) ----
    if(jt < 31){
      size_t g1 = (size_t)(k0+bn)*H_ + (j0+32) + bh2*16;
      pfb0 = *(const uint4*)&W2Th[g1]; pfb1 = *(const uint4*)&W2Th[g1+8];
      pfb2 = *(const uint4*)&W2Tm[g1]; pfb3 = *(const uint4*)&W2Tm[g1+8];
      pfb4 = *(const uint4*)&W2Tl[g1]; pfb5 = *(const uint4*)&W2Tl[g1+8];
    }
    // ---- MFMA phase: one K=32 slice, 8 split-terms, smallest-first ----
    bfrag bf[2][3];
    #pragma unroll
    for(int n2=0;n2<2;n2++){
      int bo = ((2*wv+n2)*16 + fr_m)*32 + fro;
      bf[n2][0] = *(bfrag*)&sm.st.Bt[0][bo];
      bf[n2][1] = *(bfrag*)&sm.st.Bt[1][bo];
      bf[n2][2] = *(bfrag*)&sm.st.Bt[2][bo];
    }
    #pragma unroll
    for(int mt=0; mt<5; mt++){
      int ao = (mt*16 + fr_m)*32 + fro;
      bfrag a0 = *(bfrag*)&sm.st.A[0][ao];
      bfrag a1v= *(bfrag*)&sm.st.A[1][ao];
      bfrag a2v= *(bfrag*)&sm.st.A[2][ao];
      #pragma unroll
      for(int n2=0;n2<2;n2++){
        f4v c = acc[mt][n2];
        c = __builtin_amdgcn_mfma_f32_16x16x32_bf16(a2v, bf[n2][1], c, 0,0,0); // 2^-24
        c = __builtin_amdgcn_mfma_f32_16x16x32_bf16(a1v, bf[n2][2], c, 0,0,0); // 2^-24
        c = __builtin_amdgcn_mfma_f32_16x16x32_bf16(a2v, bf[n2][0], c, 0,0,0); // 2^-16
        c = __builtin_amdgcn_mfma_f32_16x16x32_bf16(a0,  bf[n2][2], c, 0,0,0); // 2^-16
        c = __builtin_amdgcn_mfma_f32_16x16x32_bf16(a1v, bf[n2][1], c, 0,0,0); // 2^-16
        c = __builtin_amdgcn_mfma_f32_16x16x32_bf16(a1v, bf[n2][0], c, 0,0,0); // 2^-8
        c = __builtin_amdgcn_mfma_f32_16x16x32_bf16(a0,  bf[n2][1], c, 0,0,0); // 2^-8
        c = __builtin_amdgcn_mfma_f32_16x16x32_bf16(a0,  bf[n2][0], c, 0,0,0); // 1
        acc[mt][n2] = c;
      }
    }
  }

  // ---- epilogue: 2 phases (n-halves) of col-major dump + d2 contraction ----
  float Mp[44];
  #pragma unroll
  for(int i=0;i<44;i++) Mp[i]=0.f;
  int es = t>>5, ec = t&31;

  #pragma unroll
  for(int ph=0; ph<2; ph++){
    __syncthreads();
    if((wv>>1) == ph){
      int wb = wv & 1;
      #pragma unroll
      for(int mt=0; mt<5; mt++){
        #pragma unroll
        for(int n2=0;n2<2;n2++){
          int col = (2*wb+n2)*16 + fr_m;       // 0..63 within phase
          int rowb = mt*16 + fr_q*4;
          #pragma unroll
          for(int rg=0;rg<4;rg++)
            sm.Td[col*LDTD + rowb + rg] = acc[mt][n2][rg];
        }
      }
    }
    __syncthreads();
    #pragma unroll
    for(int cc=0; cc<2; cc++){
      int col = ec + cc*32;
      int kk = ph*64 + col;
      float s2v = s2[(size_t)(b0+es)*H_ + k0 + kk];
      float w3v = W3[k0 + kk];
      float d = w3v*s2v*(1.f-s2v);
      const float* tp = &sm.Td[col*LDTD + es*8];
      float4 t0 = *(const float4*)tp, t1 = *(const float4*)(tp+4);
      float T8[8] = {t0.x,t0.y,t0.z,t0.w,t1.x,t1.y,t1.z,t1.w};
      float vv = sm.Td[col*LDTD + 64 + es];
      int ix=0;
      #pragma unroll
      for(int m=0;m<8;m++){
        float w = T8[m]*d;
        Mp[36+m] += w*vv;
        #pragma unroll
        for(int n=m;n<8;n++){ Mp[ix] += w*T8[n]; ix++; }
      }
    }
  }
  // reduce over the 32 column lanes
  #pragma unroll
  for(int i=0;i<44;i++){
    #pragma unroll
    for(int off=1; off<32; off<<=1) Mp[i] += __shfl_xor(Mp[i], off, 64);
  }
  if(ec==0){
    float* o = &Mpart[((size_t)(b0+es)*8 + kb)*44];
    #pragma unroll
    for(int i=0;i<44;i++) o[i] = Mp[i];
  }
}

// ---------------- K6: assemble + f64 solve ----------------
__global__ __launch_bounds__(64) void k6(const float* __restrict__ x,
                    const float* __restrict__ Hz1M, const float* __restrict__ Mpart,
                    const float* __restrict__ dq16, float* __restrict__ out){
  __shared__ double A[64][73];
  int t = threadIdx.x;
  int b = blockIdx.x*64 + t;
  double* Ar = A[t];
  float qd[8];
  #pragma unroll
  for(int j=0;j<8;j++) qd[j] = x[b*16 + 8 + j];
  float Ms[44];
  #pragma unroll
  for(int i=0;i<44;i++) Ms[i]=0.f;
  for(int kb=0;kb<8;kb++){
    const float* mp = &Mpart[((size_t)b*8+kb)*44];
    #pragma unroll
    for(int i=0;i<44;i++) Ms[i] += mp[i];
  }
  #pragma unroll
  for(int i=0;i<8;i++){
    #pragma unroll
    for(int j=0;j<8;j++) Ar[i*9+j] = (double)Hz1M[(size_t)b*64 + i*8 + j];
    Ar[i*9+8] = (double)dq16[b*16+i] - (double)dq16[b*16+8+i] - (double)Ms[36+i];
  }
  { int ix=0;
    for(int m=0;m<8;m++)
      for(int n=m;n<8;n++){
        Ar[m*9+n] += (double)Ms[ix];
        if(n>m) Ar[n*9+m] += (double)Ms[ix];
        ix++;
      }
  }
  for(int c=0;c<8;c++){
    int piv = c; double best = fabs(Ar[c*9+c]);
    for(int rr=c+1; rr<8; rr++){ double v = fabs(Ar[rr*9+c]); if(v>best){best=v;piv=rr;} }
    if(piv!=c){
      for(int cc=c; cc<9; cc++){ double tmp=Ar[c*9+cc]; Ar[c*9+cc]=Ar[piv*9+cc]; Ar[piv*9+cc]=tmp; }
    }
    double inv = 1.0/Ar[c*9+c];
    for(int rr=c+1; rr<8; rr++){
      double f = Ar[rr*9+c]*inv;
      for(int cc=c+1; cc<9; cc++) Ar[rr*9+cc] -= f*Ar[c*9+cc];
    }
  }
  double sol[8];
  #pragma unroll
  for(int i=7;i>=0;i--){
    double s = Ar[i*9+8];
    #pragma unroll
    for(int j=i+1;j<8;j++) s -= Ar[i*9+j]*sol[j];
    sol[i] = s/Ar[i*9+i];
  }
  #pragma unroll
  for(int j=0;j<8;j++) out[b*16+j] = qd[j];
  #pragma unroll
  for(int i=0;i<8;i++) out[b*16+8+i] = (float)sol[i];
}

extern "C" void kernel_launch(void* const* d_in, const int* in_sizes, int n_in,
                              void* d_out, int out_size, void* d_ws, size_t ws_size,
                              hipStream_t stream){
  const float* x  = (const float*)d_in[0];
  const float* W1 = (const float*)d_in[1];
  const float* b1 = (const float*)d_in[2];
  const float* W2 = (const float*)d_in[3];
  const float* b2 = (const float*)d_in[4];
  const float* W3 = (const float*)d_in[5];
  float* out = (float*)d_out;

  float* ws   = (float*)d_ws;
  size_t BH   = (size_t)B_*H_;
  float* s1   = ws;                           // B*H
  float* s2   = s1  + BH;                     // B*H
  float* u    = s2  + BH;                     // B*H  (later: Mpart + W2T planes)
  float* F64  = u   + BH;                     // H*64
  float* Hz1M = F64 + (size_t)H_*64;          // B*64
  float* dq16 = Hz1M+ (size_t)B_*64;          // B*16

  // aliases inside u's 32 MB (u is dead after k5a/k5b):
  float* Mpart = u;                                        // B*8*44 fp32 = 11.5 MB
  unsigned short* W2Th = (unsigned short*)(u + 3145728);   // 12 MB offset, 2 MB
  unsigned short* W2Tm = W2Th + (size_t)H_*H_;             // 2 MB
  unsigned short* W2Tl = W2Tm + (size_t)H_*H_;             // 2 MB

  k1_s1 <<<dim3(B_),      dim3(256), 0, stream>>>(x, W1, b1, s1);
  k2_s2 <<<dim3(64,8),    dim3(256), 0, stream>>>(s1, W2, b2, s2);
  k3_u  <<<dim3(64,8),    dim3(256), 0, stream>>>(s2, W2, W3, u);
  kF    <<<dim3(256),     dim3(256), 0, stream>>>(W1, F64);
  k5a   <<<dim3(128),     dim3(256), 0, stream>>>(s1, u, F64, Hz1M);
  k5b   <<<dim3(2048),    dim3(256), 0, stream>>>(s1, u, W1, x, dq16);
  kW2T  <<<dim3(32,8),    dim3(256), 0, stream>>>(W2, W2Th, W2Tm, W2Tl);
  k4_mfma<<<dim3(8192),   dim3(256), 0, stream>>>(s1, s2, x, W1, W2Th, W2Tm, W2Tl, W3, Mpart);
  k6    <<<dim3(128),     dim3(64),  0, stream>>>(x, Hz1M, Mpart, dq16, out);
}

// Round 9
// 2433.350 us; speedup vs baseline: 1.0565x; 1.0565x over previous
//
#include <hip/hip_runtime.h>
#include <math.h>

#define B_ 8192
#define H_ 1024
#define LDP0 136
#define LDTD 100   // Td column stride (floats): 100%32=4, 16B-aligned

typedef short bfrag __attribute__((ext_vector_type(8)));
typedef float f4v  __attribute__((ext_vector_type(4)));

union U8 { unsigned short u[8]; uint4 v; };

__device__ __forceinline__ float sigf(float x){ return 1.0f/(1.0f+__expf(-x)); }

// pack high halves of two fp32 (bf16-valued) into one u32
__device__ __forceinline__ unsigned int pkhi(unsigned int u1, unsigned int u0){
  return __builtin_amdgcn_perm(u1, u0, 0x07060302u);
}

// exact 3-way truncation split of 8 fp32 -> 3 packed uint4 (bf16x8 planes)
__device__ __forceinline__ void split3(const float* av, uint4& vh, uint4& vm, uint4& vl){
  unsigned int uh[8], um[8], ul[8];
  #pragma unroll
  for(int e=0;e<8;e++){
    unsigned int ua = __float_as_uint(av[e]);
    unsigned int h = ua & 0xFFFF0000u;
    float r1 = av[e] - __uint_as_float(h);
    unsigned int mm = __float_as_uint(r1) & 0xFFFF0000u;
    float l = r1 - __uint_as_float(mm);   // exact
    uh[e]=h; um[e]=mm; ul[e]=__float_as_uint(l);
  }
  vh = make_uint4(pkhi(uh[1],uh[0]), pkhi(uh[3],uh[2]), pkhi(uh[5],uh[4]), pkhi(uh[7],uh[6]));
  vm = make_uint4(pkhi(um[1],um[0]), pkhi(um[3],um[2]), pkhi(um[5],um[4]), pkhi(um[7],um[6]));
  vl = make_uint4(pkhi(ul[1],ul[0]), pkhi(ul[3],ul[2]), pkhi(ul[5],ul[4]), pkhi(ul[7],ul[6]));
}

// ---------------- K1: s1 = sigmoid(x @ W1 + b1) ----------------
__global__ void k1_s1(const float* __restrict__ x, const float* __restrict__ W1,
                      const float* __restrict__ b1, float* __restrict__ s1o){
  __shared__ float xs[16];
  int b = blockIdx.x, t = threadIdx.x;
  if(t < 16) xs[t] = x[b*16 + t];
  __syncthreads();
  for(int h = t; h < H_; h += 256){
    float acc = b1[h];
    #pragma unroll
    for(int j=0;j<16;j++) acc += xs[j]*W1[j*H_ + h];
    s1o[(size_t)b*H_ + h] = sigf(acc);
  }
}

// ---------------- K2: s2 = sigmoid(softplus @ W2 + b2), softplus = -log(1-s1) ----
__global__ __launch_bounds__(256,3) void k2_s2(const float* __restrict__ s1,
                      const float* __restrict__ W2, const float* __restrict__ b2,
                      float* __restrict__ s2o){
  __shared__ __align__(16) float As[32*LDP0];
  __shared__ __align__(16) float Bs[32*LDP0];
  int t = threadIdx.x, tx = t & 15, ty = t >> 4;
  int m0 = blockIdx.x * 128, n0 = blockIdx.y * 128;
  int jj = t & 31, rb4 = (t >> 5) * 4;
  float acc[8][8];
  #pragma unroll
  for(int i=0;i<8;i++){
    #pragma unroll
    for(int k=0;k<8;k++) acc[i][k]=0.f; }

  for(int jt=0; jt<32; jt++){
    int j0 = jt*32;
    __syncthreads();
    #pragma unroll
    for(int g=0; g<4; g++){
      #pragma unroll
      for(int i=0;i<4;i++){
        int r = rb4 + i + 32*g;
        As[jj*LDP0 + r] = -__logf(1.0f - s1[(size_t)(m0+r)*H_ + j0 + jj]);
      }
    }
    { int jB = t >> 3, kb = (t & 7) * 16;
      const float* src = &W2[(size_t)(j0 + jB)*H_ + n0 + kb];
      #pragma unroll
      for(int c=0;c<4;c++) *(float4*)&Bs[jB*LDP0 + kb + 4*c] = *(const float4*)(src + 4*c);
    }
    __syncthreads();
    #pragma unroll 8
    for(int j=0;j<32;j++){
      float4 a0 = *(const float4*)&As[j*LDP0 + 8*ty];
      float4 a1f= *(const float4*)&As[j*LDP0 + 8*ty+4];
      float4 b0 = *(const float4*)&Bs[j*LDP0 + 4*tx];
      float4 b1f= *(const float4*)&Bs[j*LDP0 + 64 + 4*tx];
      float aa[8] = {a0.x,a0.y,a0.z,a0.w,a1f.x,a1f.y,a1f.z,a1f.w};
      float bb[8] = {b0.x,b0.y,b0.z,b0.w,b1f.x,b1f.y,b1f.z,b1f.w};
      #pragma unroll
      for(int i=0;i<8;i++){
        #pragma unroll
        for(int k=0;k<8;k++) acc[i][k] += aa[i]*bb[k]; }
    }
  }
  float4 bb0 = *(const float4*)&b2[n0 + 4*tx];
  float4 bb1 = *(const float4*)&b2[n0 + 64 + 4*tx];
  #pragma unroll
  for(int i=0;i<8;i++){
    size_t r = (size_t)(m0 + 8*ty + i)*H_;
    float4 o0 = make_float4(sigf(acc[i][0]+bb0.x), sigf(acc[i][1]+bb0.y),
                            sigf(acc[i][2]+bb0.z), sigf(acc[i][3]+bb0.w));
    float4 o1 = make_float4(sigf(acc[i][4]+bb1.x), sigf(acc[i][5]+bb1.y),
                            sigf(acc[i][6]+bb1.z), sigf(acc[i][7]+bb1.w));
    *(float4*)&s2o[r + n0 + 4*tx] = o0;
    *(float4*)&s2o[r + n0 + 64 + 4*tx] = o1;
  }
}

// ---------------- K3: u = (w3*s2) @ W2^T ----------------
__global__ __launch_bounds__(256,3) void k3_u(const float* __restrict__ s2,
                      const float* __restrict__ W2, const float* __restrict__ W3,
                      float* __restrict__ u){
  __shared__ __align__(16) float As[32*LDP0];
  __shared__ __align__(16) float Bs[32*LDP0];
  int t = threadIdx.x, tx = t & 15, ty = t >> 4;
  int m0 = blockIdx.x * 128, n0 = blockIdx.y * 128;
  int jj = t & 31, rb4 = (t >> 5) * 4;
  float acc[8][8];
  #pragma unroll
  for(int i=0;i<8;i++){
    #pragma unroll
    for(int k=0;k<8;k++) acc[i][k]=0.f; }

  for(int kt=0; kt<32; kt++){
    int k0 = kt*32;
    __syncthreads();
    float w3v = W3[k0 + jj];
    #pragma unroll
    for(int g=0; g<4; g++){
      #pragma unroll
      for(int i=0;i<4;i++){
        int r = rb4 + i + 32*g;
        As[jj*LDP0 + r] = w3v * s2[(size_t)(m0+r)*H_ + k0 + jj];
      }
    }
    { int jcol = t >> 1, kb = (t & 1) * 16;
      const float* src = &W2[(size_t)(n0 + jcol)*H_ + k0 + kb];
      #pragma unroll
      for(int c=0;c<16;c++) Bs[(kb+c)*LDP0 + jcol] = src[c];
    }
    __syncthreads();
    #pragma unroll 8
    for(int j=0;j<32;j++){
      float4 a0 = *(const float4*)&As[j*LDP0 + 8*ty];
      float4 a1f= *(const float4*)&As[j*LDP0 + 8*ty+4];
      float4 b0 = *(const float4*)&Bs[j*LDP0 + 4*tx];
      float4 b1f= *(const float4*)&Bs[j*LDP0 + 64 + 4*tx];
      float aa[8] = {a0.x,a0.y,a0.z,a0.w,a1f.x,a1f.y,a1f.z,a1f.w};
      float bb[8] = {b0.x,b0.y,b0.z,b0.w,b1f.x,b1f.y,b1f.z,b1f.w};
      #pragma unroll
      for(int i=0;i<8;i++){
        #pragma unroll
        for(int k=0;k<8;k++) acc[i][k] += aa[i]*bb[k]; }
    }
  }
  #pragma unroll
  for(int i=0;i<8;i++){
    size_t r = (size_t)(m0 + 8*ty + i)*H_;
    *(float4*)&u[r + n0 + 4*tx]      = make_float4(acc[i][0],acc[i][1],acc[i][2],acc[i][3]);
    *(float4*)&u[r + n0 + 64 + 4*tx] = make_float4(acc[i][4],acc[i][5],acc[i][6],acc[i][7]);
  }
}

// ---------------- KF: F64[j][p] = W1[8+(p>>3)][j]*W1[8+(p&7)][j] ----------------
__global__ void kF(const float* __restrict__ W1, float* __restrict__ F64){
  int e = blockIdx.x*256 + threadIdx.x;
  int j = e >> 6, p = e & 63;
  F64[e] = W1[(8+(p>>3))*H_ + j] * W1[(8+(p&7))*H_ + j];
}

// ---------------- K5a: Hz1M = D1 @ F64 ----------------
__global__ __launch_bounds__(256) void k5a(const float* __restrict__ s1,
                      const float* __restrict__ u, const float* __restrict__ F64,
                      float* __restrict__ Hz1M){
  __shared__ __align__(16) float As[32*72];
  __shared__ __align__(16) float Bs[32*72];
  int t = threadIdx.x, tx = t & 15, ty = t >> 4;
  int m0 = blockIdx.x * 64;
  int jj = t & 31, rb8 = (t >> 5) * 8;
  float acc[4][4];
  #pragma unroll
  for(int i=0;i<4;i++){
    #pragma unroll
    for(int k=0;k<4;k++) acc[i][k]=0.f; }

  for(int jt=0; jt<32; jt++){
    int j0 = jt*32;
    __syncthreads();
    #pragma unroll
    for(int g=0; g<8; g++){
      int r = rb8 + g;
      float s = s1[(size_t)(m0+r)*H_ + j0 + jj];
      As[jj*72 + r] = s*(1.0f-s)*u[(size_t)(m0+r)*H_ + j0 + jj];
    }
    { int jB = t >> 3, cb = (t & 7) * 8;
      const float* src = &F64[(j0 + jB)*64 + cb];
      *(float4*)&Bs[jB*72 + cb]   = *(const float4*)(src);
      *(float4*)&Bs[jB*72 + cb+4] = *(const float4*)(src+4);
    }
    __syncthreads();
    #pragma unroll 8
    for(int j=0;j<32;j++){
      float4 a4 = *(const float4*)&As[j*72 + 4*ty];
      float4 b4 = *(const float4*)&Bs[j*72 + 4*tx];
      float aa[4] = {a4.x,a4.y,a4.z,a4.w};
      float bb[4] = {b4.x,b4.y,b4.z,b4.w};
      #pragma unroll
      for(int i=0;i<4;i++){
        #pragma unroll
        for(int k=0;k<4;k++) acc[i][k] += aa[i]*bb[k]; }
    }
  }
  #pragma unroll
  for(int i=0;i<4;i++)
    *(float4*)&Hz1M[(size_t)(m0+4*ty+i)*64 + 4*tx] =
      make_float4(acc[i][0],acc[i][1],acc[i][2],acc[i][3]);
}

// ---------------- K5b: dq16[b][0:8]=dLdq, [8:16]=c1 ----------------
__global__ void k5b(const float* __restrict__ s1, const float* __restrict__ u,
                    const float* __restrict__ W1, const float* __restrict__ x,
                    float* __restrict__ dq16){
  int wid = threadIdx.x >> 6, lane = threadIdx.x & 63;
  int b = blockIdx.x*4 + wid;
  float qd[8];
  #pragma unroll
  for(int i=0;i<8;i++) qd[i] = x[b*16 + 8 + i];
  float accd[8] = {0,0,0,0,0,0,0,0};
  float accc[8] = {0,0,0,0,0,0,0,0};
  for(int jb=0;jb<16;jb++){
    int j = jb*64 + lane;
    float s1v = s1[(size_t)b*H_+j], uv = u[(size_t)b*H_+j];
    float g1 = s1v*uv;
    float d1 = (1.0f - s1v)*g1;
    float w1q = 0.f;
    #pragma unroll
    for(int i=0;i<8;i++){ float w = W1[i*H_+j]; accd[i] += g1*w; w1q += qd[i]*w; }
    float dw = d1*w1q;
    #pragma unroll
    for(int m=0;m<8;m++) accc[m] += dw * W1[(8+m)*H_+j];
  }
  #pragma unroll
  for(int i=0;i<8;i++){
    #pragma unroll
    for(int off=1; off<64; off<<=1){
      accd[i] += __shfl_xor(accd[i], off, 64);
      accc[i] += __shfl_xor(accc[i], off, 64);
    }
  }
  if(lane==0){
    #pragma unroll
    for(int i=0;i<8;i++){ dq16[b*16+i] = accd[i]; dq16[b*16+8+i] = accc[i]; }
  }
}

// ---------------- KW2T: W2 -> 3 transposed bf16 EXACT-truncation planes [k][j] ----
__global__ void kW2T(const float* __restrict__ W2, unsigned short* __restrict__ Wh,
                     unsigned short* __restrict__ Wm, unsigned short* __restrict__ Wl){
  __shared__ float tile[32][132];
  int j0 = blockIdx.x * 32, k0 = blockIdx.y * 128;
  int t = threadIdx.x;
  int lr = t >> 3, lc0 = (t & 7) * 16;
  const float* src = &W2[(size_t)(j0+lr)*H_ + k0 + lc0];
  #pragma unroll
  for(int c=0;c<16;c+=4) *(float4*)&tile[lr][lc0+c] = *(const float4*)(src + c);
  __syncthreads();
  int k = t >> 1;
  #pragma unroll
  for(int o2=0;o2<2;o2++){
    int oc = (t&1)*2 + o2;
    float av[8];
    #pragma unroll
    for(int e=0;e<8;e++) av[e] = tile[oc*8+e][k];
    uint4 vh, vm, vl;
    split3(av, vh, vm, vl);
    size_t o = (size_t)(k0+k)*H_ + j0 + oc*8;
    *(uint4*)&Wh[o] = vh; *(uint4*)&Wm[o] = vm; *(uint4*)&Wl[o] = vl;
  }
}

// ---------------- K4: bf16x8 exact-split MFMA T-GEMM + d2 contraction ----------------
// Fragment-major LDS for A: tile (mt,plane) = contiguous 1KB, slot == lane.
// ALL ds_read_b128/ds_write_b128 are lane-contiguous (m97 fast path, no swizzle).
// B fragments load DIRECTLY from global W2T planes (L2-hot) -- no LDS round-trip.
// Block: 8 samples x 128 k-cols, BK=32. A rows: mt0..3 = T rows (s=row>>3,m=row&7);
// mt4: rows 64-71 = G[s], 72-79 = pad (zeroed once).
__global__ __launch_bounds__(256,4) void k4_mfma(
    const float* __restrict__ s1, const float* __restrict__ s2,
    const float* __restrict__ x,  const float* __restrict__ W1,
    const unsigned short* __restrict__ W2Th, const unsigned short* __restrict__ W2Tm,
    const unsigned short* __restrict__ W2Tl,
    const float* __restrict__ W3, float* __restrict__ Mpart){
  __shared__ union {
    unsigned short A[15*512];   // [mt*3+p][slot*8], 15x1KB = 15360B
    float Td[64*LDTD];          // 25600B
  } sm;
  __shared__ float qds[8][8];

  int t = threadIdx.x;
  int wv = t >> 6, lane = t & 63;
  int kb = blockIdx.x >> 10, sgp = blockIdx.x & 1023;
  int b0 = sgp*8, k0 = kb*128;

  if(t < 64){ qds[t>>3][t&7] = x[(b0+(t>>3))*16 + 8 + (t&7)]; }
  // zero mt4 tiles (3 planes x 512 shorts = 192 uint4)
  if(t < 192){
    *(uint4*)&sm.A[12*512 + t*8] = make_uint4(0,0,0,0);
  }

  f4v acc[5][2];
  #pragma unroll
  for(int mt=0;mt<5;mt++){
    #pragma unroll
    for(int n2=0;n2<2;n2++){ acc[mt][n2][0]=0.f; acc[mt][n2][1]=0.f; acc[mt][n2][2]=0.f; acc[mt][n2][3]=0.f; }
  }

  int fr_m = lane & 15, fr_q = lane >> 4;
  // A staging (primary): thread t -> tile mt=t>>6, slot=t&63, row=mt*16+(t&15), kchunk=(t>>4)&3
  int p_mt = t >> 6;
  int p_row = p_mt*16 + (t & 15);
  int p_s = p_row >> 3, p_m = p_row & 7;
  int p_kc = (t >> 4) & 3;
  int p_off = (p_mt*3)*512 + (t & 63)*8;
  // G staging (wave 0): row4 = t&15, kchunk = t>>4 (t<64); active iff row4<8
  int g_row4 = t & 15, g_kc = t >> 4;
  // B fragment global rows (fixed per wave)
  size_t bR0 = (size_t)(k0 + (2*wv+0)*16 + fr_m)*H_;
  size_t bR1 = (size_t)(k0 + (2*wv+1)*16 + fr_m)*H_;

  for(int jt=0; jt<32; jt++){
    int j0 = jt*32;
    // ---- B fragments: direct global loads (no barrier dependency) ----
    bfrag bf0h, bf0m, bf0l, bf1h, bf1m, bf1l;
    {
      size_t ga = bR0 + j0 + fr_q*8;
      size_t gb = bR1 + j0 + fr_q*8;
      bf0h = *(const bfrag*)&W2Th[ga]; bf0m = *(const bfrag*)&W2Tm[ga]; bf0l = *(const bfrag*)&W2Tl[ga];
      bf1h = *(const bfrag*)&W2Th[gb]; bf1m = *(const bfrag*)&W2Tm[gb]; bf1l = *(const bfrag*)&W2Tl[gb];
    }
    __syncthreads();   // previous jt's A reads complete
    // ---- A stage (primary T-chunk): contiguous write at slot==lane ----
    {
      const float* wp = &W1[(size_t)(8+p_m)*H_ + j0 + p_kc*8];
      const float* sp = &s1[(size_t)(b0+p_s)*H_ + j0 + p_kc*8];
      float4 w0 = *(const float4*)wp, w1v = *(const float4*)(wp+4);
      float4 sa = *(const float4*)sp, sb = *(const float4*)(sp+4);
      float av[8];
      av[0]=w0.x*sa.x; av[1]=w0.y*sa.y; av[2]=w0.z*sa.z; av[3]=w0.w*sa.w;
      av[4]=w1v.x*sb.x; av[5]=w1v.y*sb.y; av[6]=w1v.z*sb.z; av[7]=w1v.w*sb.w;
      uint4 vh, vm, vl;
      split3(av, vh, vm, vl);
      *(uint4*)&sm.A[p_off]          = vh;
      *(uint4*)&sm.A[p_off + 512]    = vm;
      *(uint4*)&sm.A[p_off + 1024]   = vl;
    }
    // ---- G stage (wave 0, rows 64-71; pad rows stay zero) ----
    if(t < 64 && g_row4 < 8){
      int s = g_row4;
      const float* sp = &s1[(size_t)(b0+s)*H_ + j0 + g_kc*8];
      float4 sa = *(const float4*)sp, sb = *(const float4*)(sp+4);
      float g8[8] = {0,0,0,0,0,0,0,0};
      #pragma unroll
      for(int i=0;i<8;i++){
        float q = qds[s][i];
        const float* wp = &W1[(size_t)i*H_ + j0 + g_kc*8];
        float4 a0 = *(const float4*)wp, a1 = *(const float4*)(wp+4);
        g8[0] += q*a0.x; g8[1] += q*a0.y; g8[2] += q*a0.z; g8[3] += q*a0.w;
        g8[4] += q*a1.x; g8[5] += q*a1.y; g8[6] += q*a1.z; g8[7] += q*a1.w;
      }
      float av[8];
      av[0]=g8[0]*sa.x; av[1]=g8[1]*sa.y; av[2]=g8[2]*sa.z; av[3]=g8[3]*sa.w;
      av[4]=g8[4]*sb.x; av[5]=g8[5]*sb.y; av[6]=g8[6]*sb.z; av[7]=g8[7]*sb.w;
      uint4 vh, vm, vl;
      split3(av, vh, vm, vl);
      int go = 12*512 + t*8;   // slot == t within mt4 tile
      *(uint4*)&sm.A[go]        = vh;
      *(uint4*)&sm.A[go + 512]  = vm;
      *(uint4*)&sm.A[go + 1024] = vl;
    }
    __syncthreads();
    // ---- MFMA: contiguous A-frag reads; 8 split-terms, smallest-first ----
    #pragma unroll
    for(int mt=0; mt<5; mt++){
      int ab = (mt*3)*512 + lane*8;
      bfrag a0 = *(bfrag*)&sm.A[ab];
      bfrag a1v= *(bfrag*)&sm.A[ab + 512];
      bfrag a2v= *(bfrag*)&sm.A[ab + 1024];
      {
        f4v c = acc[mt][0];
        c = __builtin_amdgcn_mfma_f32_16x16x32_bf16(a2v, bf0m, c, 0,0,0); // 2^-24
        c = __builtin_amdgcn_mfma_f32_16x16x32_bf16(a1v, bf0l, c, 0,0,0); // 2^-24
        c = __builtin_amdgcn_mfma_f32_16x16x32_bf16(a2v, bf0h, c, 0,0,0); // 2^-16
        c = __builtin_amdgcn_mfma_f32_16x16x32_bf16(a0,  bf0l, c, 0,0,0); // 2^-16
        c = __builtin_amdgcn_mfma_f32_16x16x32_bf16(a1v, bf0m, c, 0,0,0); // 2^-16
        c = __builtin_amdgcn_mfma_f32_16x16x32_bf16(a1v, bf0h, c, 0,0,0); // 2^-8
        c = __builtin_amdgcn_mfma_f32_16x16x32_bf16(a0,  bf0m, c, 0,0,0); // 2^-8
        c = __builtin_amdgcn_mfma_f32_16x16x32_bf16(a0,  bf0h, c, 0,0,0); // 1
        acc[mt][0] = c;
      }
      {
        f4v c = acc[mt][1];
        c = __builtin_amdgcn_mfma_f32_16x16x32_bf16(a2v, bf1m, c, 0,0,0);
        c = __builtin_amdgcn_mfma_f32_16x16x32_bf16(a1v, bf1l, c, 0,0,0);
        c = __builtin_amdgcn_mfma_f32_16x16x32_bf16(a2v, bf1h, c, 0,0,0);
        c = __builtin_amdgcn_mfma_f32_16x16x32_bf16(a0,  bf1l, c, 0,0,0);
        c = __builtin_amdgcn_mfma_f32_16x16x32_bf16(a1v, bf1m, c, 0,0,0);
        c = __builtin_amdgcn_mfma_f32_16x16x32_bf16(a1v, bf1h, c, 0,0,0);
        c = __builtin_amdgcn_mfma_f32_16x16x32_bf16(a0,  bf1m, c, 0,0,0);
        c = __builtin_amdgcn_mfma_f32_16x16x32_bf16(a0,  bf1h, c, 0,0,0);
        acc[mt][1] = c;
      }
    }
  }

  // ---- epilogue: 2 phases (n-halves) of col-major dump + d2 contraction ----
  float Mp[44];
  #pragma unroll
  for(int i=0;i<44;i++) Mp[i]=0.f;
  int es = t>>5, ec = t&31;

  #pragma unroll
  for(int ph=0; ph<2; ph++){
    __syncthreads();
    if((wv>>1) == ph){
      int wb = wv & 1;
      #pragma unroll
      for(int mt=0; mt<5; mt++){
        #pragma unroll
        for(int n2=0;n2<2;n2++){
          int col = (2*wb+n2)*16 + fr_m;       // 0..63 within phase
          int rowb = mt*16 + fr_q*4;
          #pragma unroll
          for(int rg=0;rg<4;rg++)
            sm.Td[col*LDTD + rowb + rg] = acc[mt][n2][rg];
        }
      }
    }
    __syncthreads();
    #pragma unroll
    for(int cc=0; cc<2; cc++){
      int col = ec + cc*32;
      int kk = ph*64 + col;
      float s2v = s2[(size_t)(b0+es)*H_ + k0 + kk];
      float w3v = W3[k0 + kk];
      float d = w3v*s2v*(1.f-s2v);
      const float* tp = &sm.Td[col*LDTD + es*8];
      float4 t0 = *(const float4*)tp, t1 = *(const float4*)(tp+4);
      float T8[8] = {t0.x,t0.y,t0.z,t0.w,t1.x,t1.y,t1.z,t1.w};
      float vv = sm.Td[col*LDTD + 64 + es];
      int ix=0;
      #pragma unroll
      for(int m=0;m<8;m++){
        float w = T8[m]*d;
        Mp[36+m] += w*vv;
        #pragma unroll
        for(int n=m;n<8;n++){ Mp[ix] += w*T8[n]; ix++; }
      }
    }
  }
  // reduce over the 32 column lanes
  #pragma unroll
  for(int i=0;i<44;i++){
    #pragma unroll
    for(int off=1; off<32; off<<=1) Mp[i] += __shfl_xor(Mp[i], off, 64);
  }
  if(ec==0){
    float* o = &Mpart[((size_t)(b0+es)*8 + kb)*44];
    #pragma unroll
    for(int i=0;i<44;i++) o[i] = Mp[i];
  }
}

// ---------------- K6: assemble + f64 solve ----------------
__global__ __launch_bounds__(64) void k6(const float* __restrict__ x,
                    const float* __restrict__ Hz1M, const float* __restrict__ Mpart,
                    const float* __restrict__ dq16, float* __restrict__ out){
  __shared__ double A[64][73];
  int t = threadIdx.x;
  int b = blockIdx.x*64 + t;
  double* Ar = A[t];
  float qd[8];
  #pragma unroll
  for(int j=0;j<8;j++) qd[j] = x[b*16 + 8 + j];
  float Ms[44];
  #pragma unroll
  for(int i=0;i<44;i++) Ms[i]=0.f;
  for(int kb=0;kb<8;kb++){
    const float* mp = &Mpart[((size_t)b*8+kb)*44];
    #pragma unroll
    for(int i=0;i<44;i++) Ms[i] += mp[i];
  }
  #pragma unroll
  for(int i=0;i<8;i++){
    #pragma unroll
    for(int j=0;j<8;j++) Ar[i*9+j] = (double)Hz1M[(size_t)b*64 + i*8 + j];
    Ar[i*9+8] = (double)dq16[b*16+i] - (double)dq16[b*16+8+i] - (double)Ms[36+i];
  }
  { int ix=0;
    for(int m=0;m<8;m++)
      for(int n=m;n<8;n++){
        Ar[m*9+n] += (double)Ms[ix];
        if(n>m) Ar[n*9+m] += (double)Ms[ix];
        ix++;
      }
  }
  for(int c=0;c<8;c++){
    int piv = c; double best = fabs(Ar[c*9+c]);
    for(int rr=c+1; rr<8; rr++){ double v = fabs(Ar[rr*9+c]); if(v>best){best=v;piv=rr;} }
    if(piv!=c){
      for(int cc=c; cc<9; cc++){ double tmp=Ar[c*9+cc]; Ar[c*9+cc]=Ar[piv*9+cc]; Ar[piv*9+cc]=tmp; }
    }
    double inv = 1.0/Ar[c*9+c];
    for(int rr=c+1; rr<8; rr++){
      double f = Ar[rr*9+c]*inv;
      for(int cc=c+1; cc<9; cc++) Ar[rr*9+cc] -= f*Ar[c*9+cc];
    }
  }
  double sol[8];
  #pragma unroll
  for(int i=7;i>=0;i--){
    double s = Ar[i*9+8];
    #pragma unroll
    for(int j=i+1;j<8;j++) s -= Ar[i*9+j]*sol[j];
    sol[i] = s/Ar[i*9+i];
  }
  #pragma unroll
  for(int j=0;j<8;j++) out[b*16+j] = qd[j];
  #pragma unroll
  for(int i=0;i<8;i++) out[b*16+8+i] = (float)sol[i];
}

extern "C" void kernel_launch(void* const* d_in, const int* in_sizes, int n_in,
                              void* d_out, int out_size, void* d_ws, size_t ws_size,
                              hipStream_t stream){
  const float* x  = (const float*)d_in[0];
  const float* W1 = (const float*)d_in[1];
  const float* b1 = (const float*)d_in[2];
  const float* W2 = (const float*)d_in[3];
  const float* b2 = (const float*)d_in[4];
  const float* W3 = (const float*)d_in[5];
  float* out = (float*)d_out;

  float* ws   = (float*)d_ws;
  size_t BH   = (size_t)B_*H_;
  float* s1   = ws;                           // B*H
  float* s2   = s1  + BH;                     // B*H
  float* u    = s2  + BH;                     // B*H  (later: Mpart + W2T planes)
  float* F64  = u   + BH;                     // H*64
  float* Hz1M = F64 + (size_t)H_*64;          // B*64
  float* dq16 = Hz1M+ (size_t)B_*64;          // B*16

  // aliases inside u's 32 MB (u is dead after k5a/k5b):
  float* Mpart = u;                                        // B*8*44 fp32 = 11.5 MB
  unsigned short* W2Th = (unsigned short*)(u + 3145728);   // 12 MB offset, 2 MB
  unsigned short* W2Tm = W2Th + (size_t)H_*H_;             // 2 MB
  unsigned short* W2Tl = W2Tm + (size_t)H_*H_;             // 2 MB

  k1_s1 <<<dim3(B_),      dim3(256), 0, stream>>>(x, W1, b1, s1);
  k2_s2 <<<dim3(64,8),    dim3(256), 0, stream>>>(s1, W2, b2, s2);
  k3_u  <<<dim3(64,8),    dim3(256), 0, stream>>>(s2, W2, W3, u);
  kF    <<<dim3(256),     dim3(256), 0, stream>>>(W1, F64);
  k5a   <<<dim3(128),     dim3(256), 0, stream>>>(s1, u, F64, Hz1M);
  k5b   <<<dim3(2048),    dim3(256), 0, stream>>>(s1, u, W1, x, dq16);
  kW2T  <<<dim3(32,8),    dim3(256), 0, stream>>>(W2, W2Th, W2Tm, W2Tl);
  k4_mfma<<<dim3(8192),   dim3(256), 0, stream>>>(s1, s2, x, W1, W2Th, W2Tm, W2Tl, W3, Mpart);
  k6    <<<dim3(128),     dim3(64),  0, stream>>>(x, Hz1M, Mpart, dq16, out);
}